// Round 3
// baseline (179.603 us; speedup 1.0000x reference)
//
#include <hip/hip_runtime.h>
#include <hip/hip_bf16.h>
#include <stdint.h>

// Problem constants (SurrealEmbedding): B=8192, L=618, D=1910
#define B_   8192
#define L_   618
#define D_   1910
#define LP   640          // padded L (multiple of 32)
#define KP   1280         // K' = 2*LP  (concatenated plus/minus)
#define NP   1920         // padded D (multiple of 128)

typedef __attribute__((ext_vector_type(8))) short short8;
typedef __attribute__((ext_vector_type(4))) float f32x4;

__device__ __forceinline__ unsigned short f2bf(float f) {
  union { float f; unsigned u; } v; v.f = f;
  unsigned u = v.u;
  return (unsigned short)((u + 0x7FFFu + ((u >> 16) & 1u)) >> 16);  // RNE
}

// ---------------------------------------------------------------------------
// prep_A: A[b][2l+s] = w_l (bf16), other slot 0.  w_0=ALPHA, w_{l>=1}=1.0f.
// ---------------------------------------------------------------------------
__global__ void prep_A(const int* __restrict__ signs, const int* __restrict__ lengths,
                       unsigned* __restrict__ A2u) {
  int b = blockIdx.x;
  int n = lengths[b];
  const unsigned wb1 = 0x3F80u;                                   // bf16(1.0f)
  const unsigned wba = (unsigned)f2bf(0.61803398874989484820f);   // bf16(ALPHA)
  for (int l2 = threadIdx.x; l2 < LP; l2 += blockDim.x) {
    unsigned val = 0;
    if (l2 < L_ && l2 < n) {
      unsigned wb = (l2 == 0) ? wba : wb1;
      int s = signs[b * L_ + l2];
      val = (s == 0) ? wb : (wb << 16);
    }
    A2u[b * (KP / 2) + l2] = val;
  }
}

// ---------------------------------------------------------------------------
// prep_B: BT[d][2l] = bf16(plus[l][d]), BT[d][2l+1] = bf16(minus[l][d]).
// BT is [NP][KP] bf16 (pre-transposed), zero padding.
// ---------------------------------------------------------------------------
__global__ void prep_B(const float* __restrict__ bp, const float* __restrict__ bm,
                       unsigned* __restrict__ BTu) {
  int d = blockIdx.x * 256 + threadIdx.x;
  int l2 = blockIdx.y;
  if (d >= NP) return;
  unsigned val = 0;
  if (l2 < L_ && d < D_) {
    unsigned p = f2bf(bp[l2 * D_ + d]);
    unsigned m = f2bf(bm[l2 * D_ + d]);
    val = p | (m << 16);
  }
  BTu[d * (KP / 2) + l2] = val;
}

// ---------------------------------------------------------------------------
// GEMM: C[8192][1920] = A[8192][1280] * B[1280][1920] (B given transposed).
// 128x128 tile, BK=64, 4 waves of 64x64, 16x16x32 bf16 MFMA, XOR-swizzled LDS.
// ---------------------------------------------------------------------------
__global__ __launch_bounds__(256)
void gemm_kernel(const unsigned short* __restrict__ A2,
                 const unsigned short* __restrict__ BT,
                 float* __restrict__ out) {
  __shared__ __align__(16) short As[128 * 64];
  __shared__ __align__(16) short Bs[128 * 64];

  const int tid = threadIdx.x;
  const int l   = tid & 63;
  const int w   = tid >> 6;
  const int wm  = w >> 1, wn = w & 1;
  const int m0  = blockIdx.y * 128;
  const int n0  = blockIdx.x * 128;

  f32x4 acc[4][4] = {};
  short8 ar[4], br[4];

#pragma unroll
  for (int i = 0; i < 4; ++i) {
    int idx = (i * 256 + tid) * 8;
    int r = idx >> 6, c = idx & 63;
    ar[i] = *(const short8*)(A2 + (m0 + r) * KP + c);
    br[i] = *(const short8*)(BT + (n0 + r) * KP + c);
  }

  const int NT = KP / 64;
  for (int kt = 0; kt < NT; ++kt) {
    __syncthreads();
#pragma unroll
    for (int i = 0; i < 4; ++i) {
      int idx = (i * 256 + tid) * 8;
      int r = idx >> 6;
      int off = idx ^ ((r & 7) << 3);      // T2 swizzle, 16B slots (short units)
      *(short8*)(As + off) = ar[i];
      *(short8*)(Bs + off) = br[i];
    }
    __syncthreads();

    if (kt + 1 < NT) {
      int k0 = (kt + 1) * 64;
#pragma unroll
      for (int i = 0; i < 4; ++i) {
        int idx = (i * 256 + tid) * 8;
        int r = idx >> 6, c = idx & 63;
        ar[i] = *(const short8*)(A2 + (m0 + r) * KP + k0 + c);
        br[i] = *(const short8*)(BT + (n0 + r) * KP + k0 + c);
      }
    }

#pragma unroll
    for (int kk = 0; kk < 64; kk += 32) {
      const int cs = kk + ((l >> 4) << 3);        // short col within tile row
      short8 af[4], bf[4];
#pragma unroll
      for (int m = 0; m < 4; ++m) {
        int r = wm * 64 + m * 16 + (l & 15);
        af[m] = *(const short8*)(As + (r * 64 + (cs ^ ((r & 7) << 3))));
      }
#pragma unroll
      for (int n = 0; n < 4; ++n) {
        int r = wn * 64 + n * 16 + (l & 15);
        bf[n] = *(const short8*)(Bs + (r * 64 + (cs ^ ((r & 7) << 3))));
      }
#pragma unroll
      for (int m = 0; m < 4; ++m)
#pragma unroll
        for (int n = 0; n < 4; ++n)
          acc[m][n] = __builtin_amdgcn_mfma_f32_16x16x32_bf16(af[m], bf[n], acc[m][n], 0, 0, 0);
    }
  }

  // epilogue: C/D layout col = lane&15, row = (lane>>4)*4 + reg
  const int rl = l >> 4, cl = l & 15;
#pragma unroll
  for (int m = 0; m < 4; ++m) {
#pragma unroll
    for (int n = 0; n < 4; ++n) {
      int col = n0 + wn * 64 + n * 16 + cl;
      if (col < D_) {
        int rbase = m0 + wm * 64 + m * 16 + rl * 4;
#pragma unroll
        for (int q = 0; q < 4; ++q)
          out[(rbase + q) * D_ + col] = acc[m][n][q];
      }
    }
  }
}

// ---------------------------------------------------------------------------
// normalize: out[b,:] /= ||out[b,:]||  (norm>0 guard)
// ---------------------------------------------------------------------------
__global__ void normalize_kernel(float* __restrict__ out) {
  __shared__ float red[4];
  int b = blockIdx.x;
  float* row = out + (size_t)b * D_;
  float vals[8];
  float ss = 0.f;
#pragma unroll
  for (int j = 0; j < 8; ++j) {
    int d = threadIdx.x + j * 256;
    float v = (d < D_) ? row[d] : 0.f;
    vals[j] = v;
    ss += v * v;
  }
#pragma unroll
  for (int off = 32; off > 0; off >>= 1)
    ss += __shfl_down(ss, off, 64);
  int lane = threadIdx.x & 63, wv = threadIdx.x >> 6;
  if (lane == 0) red[wv] = ss;
  __syncthreads();
  float tot = red[0] + red[1] + red[2] + red[3];
  float inv = (tot > 0.f) ? (1.0f / sqrtf(tot)) : 1.0f;
#pragma unroll
  for (int j = 0; j < 8; ++j) {
    int d = threadIdx.x + j * 256;
    if (d < D_) row[d] = vals[j] * inv;
  }
}

extern "C" void kernel_launch(void* const* d_in, const int* in_sizes, int n_in,
                              void* d_out, int out_size, void* d_ws, size_t ws_size,
                              hipStream_t stream) {
  const int*   signs   = (const int*)d_in[0];
  const int*   lengths = (const int*)d_in[1];
  const float* bp      = (const float*)d_in[2];
  const float* bm      = (const float*)d_in[3];
  float*       out     = (float*)d_out;

  unsigned short* A2 = (unsigned short*)d_ws;                 // [8192][1280] bf16 = 21.0 MB
  unsigned short* BT = A2 + (size_t)B_ * KP;                  // [1920][1280] bf16 =  4.9 MB

  prep_A<<<B_, 256, 0, stream>>>(signs, lengths, (unsigned*)A2);
  prep_B<<<dim3(8, LP), 256, 0, stream>>>(bp, bm, (unsigned*)BT);
  gemm_kernel<<<dim3(NP / 128, B_ / 128), 256, 0, stream>>>(A2, BT, out);
  normalize_kernel<<<B_, 256, 0, stream>>>(out);
}